// Round 20
// baseline (110.994 us; speedup 1.0000x reference)
//
#include <hip/hip_runtime.h>
#include <math.h>

#define SLEN 2048
#define DMODEL 1024
#define NHEADS 16
#define DK 64
#define NBATCH 2
#define M_TOT (NBATCH * SLEN)   // 4096
#define NQKV (3 * DMODEL)       // 3072

typedef __bf16 bf16x8 __attribute__((ext_vector_type(8)));
typedef float f32x4 __attribute__((ext_vector_type(4)));
typedef float f32x16 __attribute__((ext_vector_type(16)));

// f32 -> bf16 round-to-nearest-even
static __device__ __forceinline__ unsigned short f2bf(float f) {
    unsigned int u = __float_as_uint(f);
    u += 0x7fffu + ((u >> 16) & 1u);
    return (unsigned short)(u >> 16);
}

// pack two f32 -> bf16x2 dword (lo = a, hi = b)
static __device__ __forceinline__ unsigned cvtpk(float a, float b) {
    unsigned r;
    asm("v_cvt_pk_bf16_f32 %0, %1, %2" : "=v"(r) : "v"(a), "v"(b));
    return r;
}

#if __has_builtin(__builtin_amdgcn_exp2f)
#define EXP2(x) __builtin_amdgcn_exp2f(x)
#else
#define EXP2(x) exp2f(x)
#endif

// async global->LDS, 16 B per lane. lds dest is wave-uniform base + lane*16.
static __device__ __forceinline__ void gload16(const void* g, void* l) {
    __builtin_amdgcn_global_load_lds(
        (const __attribute__((address_space(1))) unsigned int*)g,
        (__attribute__((address_space(3))) unsigned int*)l, 16, 0, 0);
}

// ---------------------------------------------------------------------------
// Fused prep: blocks [0,4096) convert x f32->bf16 (flat).
// Blocks [4096,4864): W_{q,k,v} -> MFMA B-FRAGMENT layout (R18-proven):
//   Wf[G][t2][q][n15][8]: value W[k][n], n = G*16+n15, k = t2*32 + q*8 + e.
// Blocks [4864,5120): Wo -> K-contiguous [N][K] (for the staged Wo GEMM).
// ---------------------------------------------------------------------------
__global__ __launch_bounds__(256)
void prep_all(const float* __restrict__ x,
              const float* __restrict__ Wq, const float* __restrict__ Wk,
              const float* __restrict__ Wv, const float* __restrict__ Wo,
              unsigned short* __restrict__ xb,
              unsigned short* __restrict__ Wcat,
              unsigned short* __restrict__ Wot)
{
    __shared__ float t[64][65];
    const int blk = blockIdx.x;
    const int tid = threadIdx.x;
    if (blk < 4096) {
        int i = blk * 256 + tid;
        float4 v = *(const float4*)&x[(size_t)i * 4];
        ushort4 o;
        o.x = f2bf(v.x); o.y = f2bf(v.y); o.z = f2bf(v.z); o.w = f2bf(v.w);
        *(ushort4*)&xb[(size_t)i * 4] = o;
    } else {
        const int tt = blk - 4096;
        const int widx = tt >> 8;           // 0..3
        const int t256 = tt & 255;
        const float* W = (widx == 0) ? Wq : (widx == 1) ? Wk : (widx == 2) ? Wv : Wo;
        const int c0 = (t256 & 15) * 64, r0 = (t256 >> 4) * 64;   // c0: n, r0: k
        const int tr = tid >> 4, tc = (tid & 15) * 4;
        #pragma unroll
        for (int rr = 0; rr < 4; ++rr) {
            int row = rr * 16 + tr;
            float4 v = *(const float4*)&W[(size_t)(r0 + row) * DMODEL + c0 + tc];
            t[row][tc + 0] = v.x; t[row][tc + 1] = v.y;
            t[row][tc + 2] = v.z; t[row][tc + 3] = v.w;
        }
        __syncthreads();
        if (widx < 3) {
            unsigned short* Wt = Wcat + (size_t)widx * 1048576;
            const int t2 = (r0 >> 5) + (tc >> 5);
            const int q  = (tc >> 3) & 3;
            const int e  = tc & 7;
            #pragma unroll
            for (int rr = 0; rr < 4; ++rr) {
                int orow = rr * 16 + tr;
                const int n = c0 + orow;
                const int G = n >> 4, n15 = n & 15;
                ushort4 o;
                o.x = f2bf(t[tc + 0][orow]);
                o.y = f2bf(t[tc + 1][orow]);
                o.z = f2bf(t[tc + 2][orow]);
                o.w = f2bf(t[tc + 3][orow]);
                *(ushort4*)&Wt[(size_t)G * 16384 + t2 * 512 + q * 128 + n15 * 8 + e] = o;
            }
        } else {
            #pragma unroll
            for (int rr = 0; rr < 4; ++rr) {
                int orow = rr * 16 + tr;
                ushort4 o;
                o.x = f2bf(t[tc + 0][orow]);
                o.y = f2bf(t[tc + 1][orow]);
                o.z = f2bf(t[tc + 2][orow]);
                o.w = f2bf(t[tc + 3][orow]);
                *(ushort4*)&Wot[(size_t)(c0 + orow) * DMODEL + r0 + tc] = o;
            }
        }
    }
}

// ---------------------------------------------------------------------------
// QKV GEMM, BK=128, A-only LDS staging (32 KB), B direct from L2 in fragment
// layout. 128x128 tile, 4 waves 2x2, 8 K-steps (16 barriers vs 32 at BK=64).
// All 16 B-frag loads (4 NR x 4 ks, 1 KB coalesced) issued before the barrier
// so they land under the vmcnt drain. 64 MFMA/wave/step.
// Epilogue: RoPE Q/K -> [bh][s][64]; V -> fragment layout (R12-proven bodies).
// ---------------------------------------------------------------------------
__global__ __launch_bounds__(256)
void gemm_qkv(const unsigned short* __restrict__ A,
              const unsigned short* __restrict__ Wf,
              unsigned short* __restrict__ Qd,
              unsigned short* __restrict__ Kd,
              unsigned short* __restrict__ Vtd,
              const int* __restrict__ pos)
{
    __shared__ unsigned short As[128 * 128];   // [row][128 k-elems], 32 KB
    const int tid = threadIdx.x;
    const int w = tid >> 6, l = tid & 63;
    const int m0 = blockIdx.y * 128, n0 = blockIdx.x * 128;
    const int wr = (w >> 1) * 64, wc = (w & 1) * 64;

    f32x4 acc[4][4] = {};

    // wave's B fragment base: col-group G0 = (n0+wc)>>4
    const unsigned short* wfB0 = Wf + ((size_t)((n0 + wc) >> 4)) * 16384 + l * 8;

    const int srow = l >> 4;        // staging: 4 rows per issue
    const int sslot = l & 15;       // 16-B slot within 256-B row

    for (int k0 = 0; k0 < 1024; k0 += 128) {
        // B frags direct from L2 (land under the barrier drain)
        bf16x8 bfr[4][4];
        {
            const unsigned short* wfB = wfB0 + (k0 >> 5) * 512;
            #pragma unroll
            for (int j = 0; j < 4; ++j)
                #pragma unroll
                for (int ks = 0; ks < 4; ++ks)
                    bfr[j][ks] = *(const bf16x8*)(wfB + j * 16384 + ks * 512);
        }
        // stage A tile: 8 issues/thread, issue i covers rows [w*32+i*4, +4)
        #pragma unroll
        for (int i = 0; i < 8; ++i) {
            int row = w * 32 + i * 4 + srow;
            gload16(A + (size_t)(m0 + row) * 1024 + k0 + ((sslot ^ (row & 7)) << 3),
                    (void*)(As + (w * 32 + i * 4) * 128));
        }
        __syncthreads();
        #pragma unroll
        for (int ks = 0; ks < 4; ++ks) {
            bf16x8 af[4];
            #pragma unroll
            for (int i = 0; i < 4; ++i) {
                int row = wr + i * 16 + (l & 15);
                int slot = (ks * 4 + (l >> 4)) ^ (row & 7);
                af[i] = *(const bf16x8*)((const char*)As + row * 256 + slot * 16);
            }
            __builtin_amdgcn_s_setprio(1);
            #pragma unroll
            for (int i = 0; i < 4; ++i)
                #pragma unroll
                for (int j = 0; j < 4; ++j)
                    acc[i][j] = __builtin_amdgcn_mfma_f32_16x16x32_bf16(af[i], bfr[j][ks], acc[i][j], 0, 0, 0);
            __builtin_amdgcn_s_setprio(0);
        }
        __syncthreads();
    }

    // Epilogue. C/D layout: col = lane&15, row = (lane>>4)*4 + reg.
    const int seg = (n0 + wc) >> 10;  // 0=Q 1=K 2=V (wave-uniform)
    #pragma unroll
    for (int i = 0; i < 4; ++i) {
        const int mbase = m0 + wr + i * 16 + (l >> 4) * 4;
        #pragma unroll
        for (int j = 0; j < 4; ++j) {
            const int n = n0 + wc + j * 16 + (l & 15);
            const int h = (n >> 6) & 15;
            const int d = n & 63;
            if (seg < 2) {
                unsigned short* dst = (seg == 0) ? Qd : Kd;
                const int de = d & ~1;
                const float freq = __expf((float)de * (-9.210340371976184f / 64.f));
                #pragma unroll
                for (int r = 0; r < 4; ++r) {
                    const int m = mbase + r;
                    const int b = m >> 11, s = m & 2047;
                    float v = acc[i][j][r];
                    float p2 = __shfl_xor(v, 1);   // partner column of the RoPE pair
                    float ang = (float)pos[m] * freq;
                    float sn, cs;
                    __sincosf(ang, &sn, &cs);
                    float res = ((l & 1) == 0) ? (v * cs - p2 * sn) : (p2 * sn + v * cs);
                    if (seg == 0) res *= 0.18033688011112042f;  // 0.125*log2(e)
                    dst[((size_t)(b * NHEADS + h) * SLEN + s) * DK + d] = f2bf(res);
                }
            } else {
                // V -> fragment layout: [bh][tile32][ks][mt2][hb][c31][8]
                const int b = mbase >> 11, s0 = mbase & 2047;
                const int tile = s0 >> 5, ksv = (s0 >> 4) & 1, hb = (s0 >> 3) & 1, j0 = s0 & 7;
                const int mt2v = d >> 5, c31v = d & 31;
                size_t idx = (size_t)(b * NHEADS + h) * 131072 + tile * 2048
                           + ksv * 1024 + mt2v * 512 + hb * 256 + c31v * 8 + j0;
                ushort4 o;
                o.x = f2bf(acc[i][j][0]); o.y = f2bf(acc[i][j][1]);
                o.z = f2bf(acc[i][j][2]); o.w = f2bf(acc[i][j][3]);
                *(ushort4*)&Vtd[idx] = o;
            }
        }
    }
}

// ---------------------------------------------------------------------------
// Wo GEMM: R17/R19-proven 64x128 single-buffered m97 structure, staged A+B.
// ---------------------------------------------------------------------------
__global__ __launch_bounds__(256)
void gemm_wo(const unsigned short* __restrict__ A,
             const unsigned short* __restrict__ Bt,
             float* __restrict__ C, int N, int K)
{
    constexpr int BM = 64, BN = 128;
    constexpr int MR = BM / 32, NR = BN / 32;
    __shared__ unsigned short AB[(BM + BN) * 64];
    const int tid = threadIdx.x;
    const int w = tid >> 6, l = tid & 63;
    const int m0 = blockIdx.y * BM, n0 = blockIdx.x * BN;
    const int wr = (w >> 1) * (BM / 2), wc = (w & 1) * (BN / 2);
    const int lr = l >> 3, lp = l & 7;

    f32x4 acc[MR][NR] = {};

    unsigned short* As = AB;
    unsigned short* Bs = AB + BM * 64;

    for (int k0 = 0; k0 < K; k0 += 64) {
        #pragma unroll
        for (int i = 0; i < BM / 32; ++i) {
            int row = i * 32 + w * 8 + lr;
            int s = lp ^ (row & 7);
            gload16(A + (size_t)(m0 + row) * K + k0 + s * 8, (void*)(As + (i * 32 + w * 8) * 64));
        }
        #pragma unroll
        for (int i = 0; i < BN / 32; ++i) {
            int row = i * 32 + w * 8 + lr;
            int s = lp ^ (row & 7);
            gload16(Bt + (size_t)(n0 + row) * K + k0 + s * 8, (void*)(Bs + (i * 32 + w * 8) * 64));
        }
        __syncthreads();
        #pragma unroll
        for (int ks = 0; ks < 2; ++ks) {
            bf16x8 af[MR], bfr[NR];
            #pragma unroll
            for (int i = 0; i < MR; ++i) {
                int row = wr + i * 16 + (l & 15);
                int slot = (ks * 4 + (l >> 4)) ^ (row & 7);
                af[i] = *(const bf16x8*)((const char*)As + row * 128 + slot * 16);
            }
            #pragma unroll
            for (int j = 0; j < NR; ++j) {
                int row = wc + j * 16 + (l & 15);
                int slot = (ks * 4 + (l >> 4)) ^ (row & 7);
                bfr[j] = *(const bf16x8*)((const char*)Bs + row * 128 + slot * 16);
            }
            __builtin_amdgcn_s_setprio(1);
            #pragma unroll
            for (int i = 0; i < MR; ++i)
                #pragma unroll
                for (int j = 0; j < NR; ++j)
                    acc[i][j] = __builtin_amdgcn_mfma_f32_16x16x32_bf16(af[i], bfr[j], acc[i][j], 0, 0, 0);
            __builtin_amdgcn_s_setprio(0);
        }
        __syncthreads();
    }

    #pragma unroll
    for (int i = 0; i < MR; ++i)
        #pragma unroll
        for (int j = 0; j < NR; ++j)
            #pragma unroll
            for (int r = 0; r < 4; ++r) {
                int row = m0 + wr + i * 16 + (l >> 4) * 4 + r;
                int col = n0 + wc + j * 16 + (l & 15);
                C[(size_t)row * N + col] = acc[i][j][r];
            }
}

// ---------------------------------------------------------------------------
// MFMA flash attention v11 (unchanged, proven): kv-split-2, private K staging
// with counted vmcnt, V fragment loads, fixed-shift softmax, P-exchange via
// v_permlane32_swap_b32.
// ---------------------------------------------------------------------------
__global__ __launch_bounds__(128)
void attn_mfma(const unsigned short* __restrict__ Q,
               const unsigned short* __restrict__ K,
               const unsigned short* __restrict__ Vf,
               unsigned short* __restrict__ Oa)
{
    __shared__ char smem[17408];   // [wave][2][4KB] staging; combine reuses
    const int tid = threadIdx.x;
    const int w = tid >> 6, l = tid & 63;
    const int h = l >> 5, c31 = l & 31;

    const int id = blockIdx.x;
    const int bh = (id & 7) * 4 + ((id >> 3) & 3);   // 4 bh per XCD stripe
    const int g  = 63 - (id >> 5);                   // q-group, heavy-first
    const int n_w = (g >= w) ? ((g - w) >> 1) + 1 : 0;

    const unsigned short* Qb  = Q  + (size_t)bh * SLEN * DK;
    const unsigned short* Kb  = K  + (size_t)bh * SLEN * DK;
    const unsigned short* VfB = Vf + (size_t)bh * 131072;

    const int q_g = g * 32 + c31;

    // Q B-frags (col = q, k = kb*16 + h*8)
    bf16x8 qf[4];
    #pragma unroll
    for (int kb = 0; kb < 4; ++kb)
        qf[kb] = *(const bf16x8*)(Qb + (size_t)q_g * DK + kb * 16 + h * 8);

    float lsum = 0.f;
    f32x16 oacc[2] = {};

    char* mybuf = smem + w * 8192;
    auto STAGE = [&](int t, int p) {
        char* dst = mybuf + p * 4096;
        const unsigned short* src = Kb + (size_t)t * 2048;   // 32 rows x 64
        #pragma unroll
        for (int i2 = 0; i2 < 4; ++i2) {
            int row = i2 * 8 + (l >> 3);
            gload16(src + row * 64 + (((l & 7) ^ (row & 7)) * 8), dst + i2 * 1024);
        }
    };

    if (n_w > 0) {
        STAGE(w, 0);
        if (n_w > 1) STAGE(w + 2, 1);

        for (int i = 0; i < n_w; ++i) {
            const int t = w + 2 * i;
            const bool last = (i == n_w - 1);
            if (last) { asm volatile("s_waitcnt vmcnt(0)" ::: "memory"); }
            else      { asm volatile("s_waitcnt vmcnt(4)" ::: "memory"); }
            __builtin_amdgcn_sched_barrier(0);

            // V A-frags, coalesced (base + lane*16), issued early
            bf16x8 vf0, vf1, vf2, vf3;
            {
                const unsigned short* vsrc = VfB + (size_t)t * 2048 + l * 8;
                vf0 = *(const bf16x8*)(vsrc);          // ks0 mt0
                vf1 = *(const bf16x8*)(vsrc + 512);    // ks0 mt1
                vf2 = *(const bf16x8*)(vsrc + 1024);   // ks1 mt0
                vf3 = *(const bf16x8*)(vsrc + 1536);   // ks1 mt1
            }

            // S^T = K . Q
            const char* kbuf = mybuf + (i & 1) * 4096;
            f32x16 sacc = {};
            __builtin_amdgcn_s_setprio(1);
            #pragma unroll
            for (int kb = 0; kb < 4; ++kb) {
                bf16x8 kf = *(const bf16x8*)(kbuf + c31 * 128 + ((((kb * 2 + h)) ^ (c31 & 7)) << 4));
                sacc = __builtin_amdgcn_mfma_f32_32x32x16_bf16(kf, qf[kb], sacc, 0, 0, 0);
            }
            __builtin_amdgcn_s_setprio(0);

            // causal mask: only the diagonal tile of the diagonal wave
            if (last && w == (g & 1)) {
                #pragma unroll
                for (int r = 0; r < 16; ++r) {
                    int crow = (r & 3) + 8 * (r >> 2) + 4 * h;
                    if (crow > c31) sacc[r] = -1e30f;
                }
            }

            // P = exp2(s) directly (fixed-shift softmax); per-lane partial sum
            float ps = 0.f;
            #pragma unroll
            for (int r = 0; r < 16; ++r) {
                float e = EXP2(sacc[r]);
                sacc[r] = e;
                ps += e;
            }
            lsum += ps;

            // O^T += V^T . P^T ; B-frag via 2 permlane32_swap
            #pragma unroll
            for (int ks = 0; ks < 2; ++ks) {
                const int rb = ks * 8;
                unsigned pk0 = cvtpk(sacc[rb + 0], sacc[rb + 1]);
                unsigned pk1 = cvtpk(sacc[rb + 2], sacc[rb + 3]);
                unsigned pk2 = cvtpk(sacc[rb + 4], sacc[rb + 5]);
                unsigned pk3 = cvtpk(sacc[rb + 6], sacc[rb + 7]);
                asm("v_permlane32_swap_b32 %0, %1" : "+v"(pk0), "+v"(pk2));
                asm("v_permlane32_swap_b32 %0, %1" : "+v"(pk1), "+v"(pk3));
                union { unsigned u[4]; bf16x8 v; } pf;
                pf.u[0] = pk0;
                pf.u[1] = pk1;
                pf.u[2] = pk2;
                pf.u[3] = pk3;
                __builtin_amdgcn_s_setprio(1);
                oacc[0] = __builtin_amdgcn_mfma_f32_32x32x16_bf16(ks ? vf2 : vf0, pf.v, oacc[0], 0, 0, 0);
                oacc[1] = __builtin_amdgcn_mfma_f32_32x32x16_bf16(ks ? vf3 : vf1, pf.v, oacc[1], 0, 0, 0);
                __builtin_amdgcn_s_setprio(0);
            }

            if (i + 2 < n_w) STAGE(w + 2 * (i + 2), i & 1);
        }
    }

    // ---- 2-way kv-split combine (plain sums; fixed shift => no weights) ----
    __syncthreads();
    float* Ll = (float*)(smem + 16384);          // [2][2][32]
    Ll[(w * 2 + h) * 32 + c31] = lsum;
    __syncthreads();
    const float lstar = Ll[c31] + Ll[32 + c31] + Ll[64 + c31] + Ll[96 + c31];

    float* Op = (float*)smem;                    // [2][16][64] f32 = 8KB
    if (w == 0) {
        #pragma unroll
        for (int mt = 0; mt < 2; ++mt)
            #pragma unroll
            for (int r = 0; r < 16; ++r)
                Op[(mt * 16 + r) * 64 + l] = oacc[mt][r];
    }
    __syncthreads();
    if (w == 1) {
        const float inv = 1.f / lstar;
        unsigned short* Os = (unsigned short*)(smem + 8192);   // [32 q][64 d] 4KB
        #pragma unroll
        for (int mt = 0; mt < 2; ++mt)
            #pragma unroll
            for (int rq = 0; rq < 4; ++rq) {
                float a0 = (Op[(mt * 16 + rq * 4 + 0) * 64 + l] + oacc[mt][rq * 4 + 0]) * inv;
                float a1 = (Op[(mt * 16 + rq * 4 + 1) * 64 + l] + oacc[mt][rq * 4 + 1]) * inv;
                float a2 = (Op[(mt * 16 + rq * 4 + 2) * 64 + l] + oacc[mt][rq * 4 + 2]) * inv;
                float a3 = (Op[(mt * 16 + rq * 4 + 3) * 64 + l] + oacc[mt][rq * 4 + 3]) * inv;
                uint2 pv;
                pv.x = cvtpk(a0, a1);
                pv.y = cvtpk(a2, a3);
                int dbyte = mt * 64 + rq * 16 + h * 8;
                *(uint2*)((char*)Os + c31 * 128 + (dbyte ^ ((c31 & 7) << 4))) = pv;
            }
        // store 32 q rows x 128B (coalesced)
        const int b = bh >> 4, hh = bh & 15;
        const int cc = l & 7;
        #pragma unroll
        for (int pp = 0; pp < 4; ++pp) {
            int row = pp * 8 + (l >> 3);
            uint4 vv = *(const uint4*)((const char*)Os + row * 128 + ((cc ^ (row & 7)) << 4));
            int srow = g * 32 + row;
            *(uint4*)&Oa[((size_t)(b * SLEN + srow)) * DMODEL + hh * DK + cc * 8] = vv;
        }
    }
}

extern "C" void kernel_launch(void* const* d_in, const int* in_sizes, int n_in,
                              void* d_out, int out_size, void* d_ws, size_t ws_size,
                              hipStream_t stream)
{
    const float* x  = (const float*)d_in[0];
    const float* Wq = (const float*)d_in[1];
    const float* Wk = (const float*)d_in[2];
    const float* Wv = (const float*)d_in[3];
    const float* Wo = (const float*)d_in[4];
    const int*  pos = (const int*)d_in[5];
    float* out = (float*)d_out;

    char* ws = (char*)d_ws;
    const size_t MB = 1024 * 1024;
    unsigned short* xb   = (unsigned short*)(ws);             // 8 MB
    unsigned short* Wcat = (unsigned short*)(ws + 8 * MB);    // 6 MB (Wf frag layout Q|K|V)
    unsigned short* Wot  = (unsigned short*)(ws + 14 * MB);   // 2 MB (K-contiguous)
    unsigned short* Qws  = (unsigned short*)(ws + 16 * MB);   // 8 MB [32][2048][64]
    unsigned short* Kws  = (unsigned short*)(ws + 24 * MB);   // 8 MB [32][2048][64]
    unsigned short* Vfws = (unsigned short*)(ws + 32 * MB);   // 8 MB fragment layout
    unsigned short* attb = (unsigned short*)(ws + 40 * MB);   // 8 MB [4096][1024]

    prep_all<<<5120, 256, 0, stream>>>(x, Wq, Wk, Wv, Wo, xb, Wcat, Wot);

    gemm_qkv<<<dim3(NQKV / 128, M_TOT / 128), 256, 0, stream>>>(
        xb, Wcat, Qws, Kws, Vfws, pos);

    attn_mfma<<<2048, 128, 0, stream>>>(Qws, Kws, Vfws, attb);

    gemm_wo<<<dim3(DMODEL / 128, M_TOT / 64), 256, 0, stream>>>(
        attb, Wot, out, DMODEL, DMODEL);
}

// Round 21
// 99.893 us; speedup vs baseline: 1.1111x; 1.1111x over previous
//
#include <hip/hip_runtime.h>
#include <math.h>

#define SLEN 2048
#define DMODEL 1024
#define NHEADS 16
#define DK 64
#define NBATCH 2
#define M_TOT (NBATCH * SLEN)   // 4096
#define NQKV (3 * DMODEL)       // 3072

typedef __bf16 bf16x8 __attribute__((ext_vector_type(8)));
typedef float f32x4 __attribute__((ext_vector_type(4)));
typedef float f32x16 __attribute__((ext_vector_type(16)));

// f32 -> bf16 round-to-nearest-even
static __device__ __forceinline__ unsigned short f2bf(float f) {
    unsigned int u = __float_as_uint(f);
    u += 0x7fffu + ((u >> 16) & 1u);
    return (unsigned short)(u >> 16);
}

// pack two f32 -> bf16x2 dword (lo = a, hi = b)
static __device__ __forceinline__ unsigned cvtpk(float a, float b) {
    unsigned r;
    asm("v_cvt_pk_bf16_f32 %0, %1, %2" : "=v"(r) : "v"(a), "v"(b));
    return r;
}

#if __has_builtin(__builtin_amdgcn_exp2f)
#define EXP2(x) __builtin_amdgcn_exp2f(x)
#else
#define EXP2(x) exp2f(x)
#endif

// async global->LDS, 16 B per lane. lds dest is wave-uniform base + lane*16.
static __device__ __forceinline__ void gload16(const void* g, void* l) {
    __builtin_amdgcn_global_load_lds(
        (const __attribute__((address_space(1))) unsigned int*)g,
        (__attribute__((address_space(3))) unsigned int*)l, 16, 0, 0);
}

// ---------------------------------------------------------------------------
// Fused prep: blocks [0,4096) convert x f32->bf16 (flat); blocks [4096,5120)
// transpose the four weight matrices into bf16 K-contiguous layout.
// ---------------------------------------------------------------------------
__global__ __launch_bounds__(256)
void prep_all(const float* __restrict__ x,
              const float* __restrict__ Wq, const float* __restrict__ Wk,
              const float* __restrict__ Wv, const float* __restrict__ Wo,
              unsigned short* __restrict__ xb,
              unsigned short* __restrict__ Wcat,
              unsigned short* __restrict__ Wot)
{
    __shared__ float t[64][65];
    const int blk = blockIdx.x;
    const int tid = threadIdx.x;
    if (blk < 4096) {
        int i = blk * 256 + tid;
        float4 v = *(const float4*)&x[(size_t)i * 4];
        ushort4 o;
        o.x = f2bf(v.x); o.y = f2bf(v.y); o.z = f2bf(v.z); o.w = f2bf(v.w);
        *(ushort4*)&xb[(size_t)i * 4] = o;
    } else {
        const int tt = blk - 4096;
        const int widx = tt >> 8;           // 0..3
        const int t256 = tt & 255;
        const float* W = (widx == 0) ? Wq : (widx == 1) ? Wk : (widx == 2) ? Wv : Wo;
        unsigned short* Wt = (widx < 3) ? (Wcat + (size_t)widx * 1048576) : Wot;
        const int c0 = (t256 & 15) * 64, r0 = (t256 >> 4) * 64;
        const int tr = tid >> 4, tc = (tid & 15) * 4;
        #pragma unroll
        for (int rr = 0; rr < 4; ++rr) {
            int row = rr * 16 + tr;
            float4 v = *(const float4*)&W[(size_t)(r0 + row) * DMODEL + c0 + tc];
            t[row][tc + 0] = v.x; t[row][tc + 1] = v.y;
            t[row][tc + 2] = v.z; t[row][tc + 3] = v.w;
        }
        __syncthreads();
        #pragma unroll
        for (int rr = 0; rr < 4; ++rr) {
            int orow = rr * 16 + tr;
            ushort4 o;
            o.x = f2bf(t[tc + 0][orow]);
            o.y = f2bf(t[tc + 1][orow]);
            o.z = f2bf(t[tc + 2][orow]);
            o.w = f2bf(t[tc + 3][orow]);
            *(ushort4*)&Wt[(size_t)(c0 + orow) * DMODEL + r0 + tc] = o;
        }
    }
}

// ---------------------------------------------------------------------------
// bf16 MFMA GEMM, templated tile: C[M,N] = A[M,K] @ Bt[N,K]^T.
// BM x BN tile, BK=64, 4 waves in 2x2 (each wave BM/2 x BN/2).
// SINGLE-buffered LDS, m97 structure (R12/R17/R19-proven best for this shape).
// MODE 0: C f32 [M][N]          (att @ Wo -> d_out)
// MODE 1: N=3072 QKV fused; Q (scaled 0.125*log2e), K -> [bh][s][64];
//         V -> Vf fragment layout [bh][tile32][ks][mt2][hb][c31][8]
// ---------------------------------------------------------------------------
template<int BM, int BN, int MODE>
__global__ __launch_bounds__(256)
void gemm_mfma(const unsigned short* __restrict__ A,
               const unsigned short* __restrict__ Bt,
               float* __restrict__ C,
               unsigned short* __restrict__ Qd,
               unsigned short* __restrict__ Kd,
               unsigned short* __restrict__ Vtd,
               const int* __restrict__ pos,
               int N, int K)
{
    constexpr int MR = BM / 32;   // A-frags per wave
    constexpr int NR = BN / 32;   // B-frags per wave
    __shared__ unsigned short AB[(BM + BN) * 64];
    const int tid = threadIdx.x;
    const int w = tid >> 6, l = tid & 63;
    const int m0 = blockIdx.y * BM, n0 = blockIdx.x * BN;
    const int wr = (w >> 1) * (BM / 2), wc = (w & 1) * (BN / 2);
    const int lr = l >> 3, lp = l & 7;

    f32x4 acc[MR][NR] = {};

    unsigned short* As = AB;
    unsigned short* Bs = AB + BM * 64;

    for (int k0 = 0; k0 < K; k0 += 64) {
        #pragma unroll
        for (int i = 0; i < BM / 32; ++i) {
            int row = i * 32 + w * 8 + lr;
            int s = lp ^ (row & 7);
            gload16(A + (size_t)(m0 + row) * K + k0 + s * 8, (void*)(As + (i * 32 + w * 8) * 64));
        }
        #pragma unroll
        for (int i = 0; i < BN / 32; ++i) {
            int row = i * 32 + w * 8 + lr;
            int s = lp ^ (row & 7);
            gload16(Bt + (size_t)(n0 + row) * K + k0 + s * 8, (void*)(Bs + (i * 32 + w * 8) * 64));
        }
        __syncthreads();
        #pragma unroll
        for (int ks = 0; ks < 2; ++ks) {
            bf16x8 af[MR], bfr[NR];
            #pragma unroll
            for (int i = 0; i < MR; ++i) {
                int row = wr + i * 16 + (l & 15);
                int slot = (ks * 4 + (l >> 4)) ^ (row & 7);
                af[i] = *(const bf16x8*)((const char*)As + row * 128 + slot * 16);
            }
            #pragma unroll
            for (int j = 0; j < NR; ++j) {
                int row = wc + j * 16 + (l & 15);
                int slot = (ks * 4 + (l >> 4)) ^ (row & 7);
                bfr[j] = *(const bf16x8*)((const char*)Bs + row * 128 + slot * 16);
            }
            __builtin_amdgcn_s_setprio(1);
            #pragma unroll
            for (int i = 0; i < MR; ++i)
                #pragma unroll
                for (int j = 0; j < NR; ++j)
                    acc[i][j] = __builtin_amdgcn_mfma_f32_16x16x32_bf16(af[i], bfr[j], acc[i][j], 0, 0, 0);
            __builtin_amdgcn_s_setprio(0);
        }
        __syncthreads();
    }

    // Epilogue. C/D layout: col = lane&15, row = (lane>>4)*4 + reg.
    if (MODE == 0) {
        #pragma unroll
        for (int i = 0; i < MR; ++i)
            #pragma unroll
            for (int j = 0; j < NR; ++j)
                #pragma unroll
                for (int r = 0; r < 4; ++r) {
                    int row = m0 + wr + i * 16 + (l >> 4) * 4 + r;
                    int col = n0 + wc + j * 16 + (l & 15);
                    C[(size_t)row * N + col] = acc[i][j][r];
                }
    } else {
        const int seg = (n0 + wc) >> 10;  // 0=Q 1=K 2=V (wave-uniform)
        #pragma unroll
        for (int i = 0; i < MR; ++i) {
            const int mbase = m0 + wr + i * 16 + (l >> 4) * 4;
            #pragma unroll
            for (int j = 0; j < NR; ++j) {
                const int n = n0 + wc + j * 16 + (l & 15);
                const int h = (n >> 6) & 15;
                const int d = n & 63;
                if (seg < 2) {
                    unsigned short* dst = (seg == 0) ? Qd : Kd;
                    const int de = d & ~1;
                    const float freq = __expf((float)de * (-9.210340371976184f / 64.f));
                    #pragma unroll
                    for (int r = 0; r < 4; ++r) {
                        const int m = mbase + r;
                        const int b = m >> 11, s = m & 2047;
                        float v = acc[i][j][r];
                        float p2 = __shfl_xor(v, 1);   // partner column of the RoPE pair
                        float ang = (float)pos[m] * freq;
                        float sn, cs;
                        __sincosf(ang, &sn, &cs);
                        float res = ((l & 1) == 0) ? (v * cs - p2 * sn) : (p2 * sn + v * cs);
                        if (seg == 0) res *= 0.18033688011112042f;  // 0.125*log2(e)
                        dst[((size_t)(b * NHEADS + h) * SLEN + s) * DK + d] = f2bf(res);
                    }
                } else {
                    // V -> fragment layout: [bh][tile32][ks][mt2][hb][c31][8]
                    const int b = mbase >> 11, s0 = mbase & 2047;
                    const int tile = s0 >> 5, ksv = (s0 >> 4) & 1, hb = (s0 >> 3) & 1, j0 = s0 & 7;
                    const int mt2v = d >> 5, c31v = d & 31;
                    size_t idx = (size_t)(b * NHEADS + h) * 131072 + tile * 2048
                               + ksv * 1024 + mt2v * 512 + hb * 256 + c31v * 8 + j0;
                    ushort4 o;
                    o.x = f2bf(acc[i][j][0]); o.y = f2bf(acc[i][j][1]);
                    o.z = f2bf(acc[i][j][2]); o.w = f2bf(acc[i][j][3]);
                    *(ushort4*)&Vtd[idx] = o;
                }
            }
        }
    }
}

// ---------------------------------------------------------------------------
// MFMA flash attention v11 (unchanged, proven): kv-split-2, private K staging
// with counted vmcnt, V fragment loads, fixed-shift softmax, P-exchange via
// v_permlane32_swap_b32.
// ---------------------------------------------------------------------------
__global__ __launch_bounds__(128)
void attn_mfma(const unsigned short* __restrict__ Q,
               const unsigned short* __restrict__ K,
               const unsigned short* __restrict__ Vf,
               unsigned short* __restrict__ Oa)
{
    __shared__ char smem[17408];   // [wave][2][4KB] staging; combine reuses
    const int tid = threadIdx.x;
    const int w = tid >> 6, l = tid & 63;
    const int h = l >> 5, c31 = l & 31;

    const int id = blockIdx.x;
    const int bh = (id & 7) * 4 + ((id >> 3) & 3);   // 4 bh per XCD stripe
    const int g  = 63 - (id >> 5);                   // q-group, heavy-first
    const int n_w = (g >= w) ? ((g - w) >> 1) + 1 : 0;

    const unsigned short* Qb  = Q  + (size_t)bh * SLEN * DK;
    const unsigned short* Kb  = K  + (size_t)bh * SLEN * DK;
    const unsigned short* VfB = Vf + (size_t)bh * 131072;

    const int q_g = g * 32 + c31;

    // Q B-frags (col = q, k = kb*16 + h*8)
    bf16x8 qf[4];
    #pragma unroll
    for (int kb = 0; kb < 4; ++kb)
        qf[kb] = *(const bf16x8*)(Qb + (size_t)q_g * DK + kb * 16 + h * 8);

    float lsum = 0.f;
    f32x16 oacc[2] = {};

    char* mybuf = smem + w * 8192;
    auto STAGE = [&](int t, int p) {
        char* dst = mybuf + p * 4096;
        const unsigned short* src = Kb + (size_t)t * 2048;   // 32 rows x 64
        #pragma unroll
        for (int i2 = 0; i2 < 4; ++i2) {
            int row = i2 * 8 + (l >> 3);
            gload16(src + row * 64 + (((l & 7) ^ (row & 7)) * 8), dst + i2 * 1024);
        }
    };

    if (n_w > 0) {
        STAGE(w, 0);
        if (n_w > 1) STAGE(w + 2, 1);

        for (int i = 0; i < n_w; ++i) {
            const int t = w + 2 * i;
            const bool last = (i == n_w - 1);
            if (last) { asm volatile("s_waitcnt vmcnt(0)" ::: "memory"); }
            else      { asm volatile("s_waitcnt vmcnt(4)" ::: "memory"); }
            __builtin_amdgcn_sched_barrier(0);

            // V A-frags, coalesced (base + lane*16), issued early
            bf16x8 vf0, vf1, vf2, vf3;
            {
                const unsigned short* vsrc = VfB + (size_t)t * 2048 + l * 8;
                vf0 = *(const bf16x8*)(vsrc);          // ks0 mt0
                vf1 = *(const bf16x8*)(vsrc + 512);    // ks0 mt1
                vf2 = *(const bf16x8*)(vsrc + 1024);   // ks1 mt0
                vf3 = *(const bf16x8*)(vsrc + 1536);   // ks1 mt1
            }

            // S^T = K . Q
            const char* kbuf = mybuf + (i & 1) * 4096;
            f32x16 sacc = {};
            __builtin_amdgcn_s_setprio(1);
            #pragma unroll
            for (int kb = 0; kb < 4; ++kb) {
                bf16x8 kf = *(const bf16x8*)(kbuf + c31 * 128 + ((((kb * 2 + h)) ^ (c31 & 7)) << 4));
                sacc = __builtin_amdgcn_mfma_f32_32x32x16_bf16(kf, qf[kb], sacc, 0, 0, 0);
            }
            __builtin_amdgcn_s_setprio(0);

            // causal mask: only the diagonal tile of the diagonal wave
            if (last && w == (g & 1)) {
                #pragma unroll
                for (int r = 0; r < 16; ++r) {
                    int crow = (r & 3) + 8 * (r >> 2) + 4 * h;
                    if (crow > c31) sacc[r] = -1e30f;
                }
            }

            // P = exp2(s) directly (fixed-shift softmax); per-lane partial sum
            float ps = 0.f;
            #pragma unroll
            for (int r = 0; r < 16; ++r) {
                float e = EXP2(sacc[r]);
                sacc[r] = e;
                ps += e;
            }
            lsum += ps;

            // O^T += V^T . P^T ; B-frag via 2 permlane32_swap
            #pragma unroll
            for (int ks = 0; ks < 2; ++ks) {
                const int rb = ks * 8;
                unsigned pk0 = cvtpk(sacc[rb + 0], sacc[rb + 1]);
                unsigned pk1 = cvtpk(sacc[rb + 2], sacc[rb + 3]);
                unsigned pk2 = cvtpk(sacc[rb + 4], sacc[rb + 5]);
                unsigned pk3 = cvtpk(sacc[rb + 6], sacc[rb + 7]);
                asm("v_permlane32_swap_b32 %0, %1" : "+v"(pk0), "+v"(pk2));
                asm("v_permlane32_swap_b32 %0, %1" : "+v"(pk1), "+v"(pk3));
                union { unsigned u[4]; bf16x8 v; } pf;
                pf.u[0] = pk0;
                pf.u[1] = pk1;
                pf.u[2] = pk2;
                pf.u[3] = pk3;
                __builtin_amdgcn_s_setprio(1);
                oacc[0] = __builtin_amdgcn_mfma_f32_32x32x16_bf16(ks ? vf2 : vf0, pf.v, oacc[0], 0, 0, 0);
                oacc[1] = __builtin_amdgcn_mfma_f32_32x32x16_bf16(ks ? vf3 : vf1, pf.v, oacc[1], 0, 0, 0);
                __builtin_amdgcn_s_setprio(0);
            }

            if (i + 2 < n_w) STAGE(w + 2 * (i + 2), i & 1);
        }
    }

    // ---- 2-way kv-split combine (plain sums; fixed shift => no weights) ----
    __syncthreads();
    float* Ll = (float*)(smem + 16384);          // [2][2][32]
    Ll[(w * 2 + h) * 32 + c31] = lsum;
    __syncthreads();
    const float lstar = Ll[c31] + Ll[32 + c31] + Ll[64 + c31] + Ll[96 + c31];

    float* Op = (float*)smem;                    // [2][16][64] f32 = 8KB
    if (w == 0) {
        #pragma unroll
        for (int mt = 0; mt < 2; ++mt)
            #pragma unroll
            for (int r = 0; r < 16; ++r)
                Op[(mt * 16 + r) * 64 + l] = oacc[mt][r];
    }
    __syncthreads();
    if (w == 1) {
        const float inv = 1.f / lstar;
        unsigned short* Os = (unsigned short*)(smem + 8192);   // [32 q][64 d] 4KB
        #pragma unroll
        for (int mt = 0; mt < 2; ++mt)
            #pragma unroll
            for (int rq = 0; rq < 4; ++rq) {
                float a0 = (Op[(mt * 16 + rq * 4 + 0) * 64 + l] + oacc[mt][rq * 4 + 0]) * inv;
                float a1 = (Op[(mt * 16 + rq * 4 + 1) * 64 + l] + oacc[mt][rq * 4 + 1]) * inv;
                float a2 = (Op[(mt * 16 + rq * 4 + 2) * 64 + l] + oacc[mt][rq * 4 + 2]) * inv;
                float a3 = (Op[(mt * 16 + rq * 4 + 3) * 64 + l] + oacc[mt][rq * 4 + 3]) * inv;
                uint2 pv;
                pv.x = cvtpk(a0, a1);
                pv.y = cvtpk(a2, a3);
                int dbyte = mt * 64 + rq * 16 + h * 8;
                *(uint2*)((char*)Os + c31 * 128 + (dbyte ^ ((c31 & 7) << 4))) = pv;
            }
        // store 32 q rows x 128B (coalesced)
        const int b = bh >> 4, hh = bh & 15;
        const int cc = l & 7;
        #pragma unroll
        for (int pp = 0; pp < 4; ++pp) {
            int row = pp * 8 + (l >> 3);
            uint4 vv = *(const uint4*)((const char*)Os + row * 128 + ((cc ^ (row & 7)) << 4));
            int srow = g * 32 + row;
            *(uint4*)&Oa[((size_t)(b * SLEN + srow)) * DMODEL + hh * DK + cc * 8] = vv;
        }
    }
}

extern "C" void kernel_launch(void* const* d_in, const int* in_sizes, int n_in,
                              void* d_out, int out_size, void* d_ws, size_t ws_size,
                              hipStream_t stream)
{
    const float* x  = (const float*)d_in[0];
    const float* Wq = (const float*)d_in[1];
    const float* Wk = (const float*)d_in[2];
    const float* Wv = (const float*)d_in[3];
    const float* Wo = (const float*)d_in[4];
    const int*  pos = (const int*)d_in[5];
    float* out = (float*)d_out;

    char* ws = (char*)d_ws;
    const size_t MB = 1024 * 1024;
    unsigned short* xb   = (unsigned short*)(ws);             // 8 MB
    unsigned short* Wcat = (unsigned short*)(ws + 8 * MB);    // 6 MB
    unsigned short* Wot  = (unsigned short*)(ws + 14 * MB);   // 2 MB
    unsigned short* Qws  = (unsigned short*)(ws + 16 * MB);   // 8 MB [32][2048][64]
    unsigned short* Kws  = (unsigned short*)(ws + 24 * MB);   // 8 MB [32][2048][64]
    unsigned short* Vfws = (unsigned short*)(ws + 32 * MB);   // 8 MB fragment layout
    unsigned short* attb = (unsigned short*)(ws + 40 * MB);   // 8 MB [4096][1024]

    prep_all<<<5120, 256, 0, stream>>>(x, Wq, Wk, Wv, Wo, xb, Wcat, Wot);

    gemm_mfma<128, 128, 1><<<dim3(NQKV / 128, M_TOT / 128), 256, 0, stream>>>(
        xb, Wcat, nullptr, Qws, Kws, Vfws, pos, NQKV, DMODEL);

    attn_mfma<<<2048, 128, 0, stream>>>(Qws, Kws, Vfws, attb);

    gemm_mfma<64, 128, 0><<<dim3(DMODEL / 128, M_TOT / 64), 256, 0, stream>>>(
        attb, Wot, out, nullptr, nullptr, nullptr, nullptr, DMODEL, DMODEL);
}